// Round 1
// 55003.009 us; speedup vs baseline: 1.0068x; 1.0068x over previous
//
#include <hip/hip_runtime.h>

typedef _Float16 f16;
typedef _Float16 f16x8 __attribute__((ext_vector_type(8)));
typedef float f32x4 __attribute__((ext_vector_type(4)));

// Problem constants (fixed by reference): B=128, T=512, UNITS=OUT=1024
#define BATCH 128
#define TSTEPS 512
#define UNITS 1024
#define MTOT (BATCH * TSTEPS) // 65536
#define NWG 256               // recur grid size (1 WG / CU, cooperative)

__device__ __forceinline__ float sigm(float x) { return 1.f / (1.f + __expf(-x)); }
__device__ __forceinline__ float tanh_f(float x) { return 2.f / (1.f + __expf(-2.f * x)) - 1.f; }

// ---------------------------------------------------------------------------
// Transpose + fp32->fp16 convert: in[K][N] -> out[N][K]
// ---------------------------------------------------------------------------
__global__ void transpose_cvt(const float* __restrict__ in, f16* __restrict__ out,
                              int K, int N) {
  __shared__ float tile[32][33];
  int bx = blockIdx.x * 32, by = blockIdx.y * 32;
  int x = threadIdx.x, y = threadIdx.y;
#pragma unroll
  for (int i = 0; i < 32; i += 8)
    tile[y + i][x] = in[(size_t)(by + y + i) * N + bx + x];
  __syncthreads();
#pragma unroll
  for (int i = 0; i < 32; i += 8)
    out[(size_t)(bx + y + i) * K + by + x] = (f16)tile[x][y + i];
}

// ---------------------------------------------------------------------------
// h0 fp32 -> f16 into h ping-pong buffer slot 0
// ---------------------------------------------------------------------------
__global__ void cvt_h0(const float* __restrict__ h0, f16* __restrict__ hb) {
  int i = blockIdx.x * blockDim.x + threadIdx.x;
  if (i < BATCH * UNITS) hb[i] = (f16)h0[i];
}

// ---------------------------------------------------------------------------
// E = relu(X @ W_emb + b_emb), stored f16, rows ordered m = t*128 + b
// X is target_inputs [128][513][1024] fp32; WT is W_emb^T f16 [1024][1024]
// ---------------------------------------------------------------------------
__global__ __launch_bounds__(256) void emb_gemm(const float* __restrict__ X,
                                                const f16* __restrict__ WT,
                                                const float* __restrict__ bias,
                                                f16* __restrict__ Eout) {
  __shared__ f16 As[128][40]; // +8 pad: 2-way LDS aliasing only (free)
  __shared__ f16 Bs[128][40];
  const int bm = blockIdx.x, bn = blockIdx.y;
  const int tid = threadIdx.x, lane = tid & 63, wave = tid >> 6;
  const int wm = (wave >> 1) * 64, wn = (wave & 1) * 64;
  const int row = lane & 15, q8 = (lane >> 4) * 8;
  f32x4 acc[4][4] = {};
  for (int k0 = 0; k0 < UNITS; k0 += 32) {
    for (int i = tid; i < 512; i += 256) {
      int r = i >> 2, cc = (i & 3) * 8;
      int m = bm * 128 + r;
      int b = m & 127, t = m >> 7;
      const float* src = X + (size_t)(b * 513 + t) * 1024 + k0 + cc;
      float4 v0 = *(const float4*)src;
      float4 v1 = *(const float4*)(src + 4);
      f16x8 v = {(f16)v0.x, (f16)v0.y, (f16)v0.z, (f16)v0.w,
                 (f16)v1.x, (f16)v1.y, (f16)v1.z, (f16)v1.w};
      *(f16x8*)&As[r][cc] = v;
    }
    for (int i = tid; i < 512; i += 256) {
      int r = i >> 2, cc = (i & 3) * 8;
      *(f16x8*)&Bs[r][cc] = *(const f16x8*)(WT + (size_t)(bn * 128 + r) * 1024 + k0 + cc);
    }
    __syncthreads();
    f16x8 af[4], bf[4];
#pragma unroll
    for (int i = 0; i < 4; ++i) af[i] = *(const f16x8*)&As[wm + i * 16 + row][q8];
#pragma unroll
    for (int j = 0; j < 4; ++j) bf[j] = *(const f16x8*)&Bs[wn + j * 16 + row][q8];
#pragma unroll
    for (int i = 0; i < 4; ++i)
#pragma unroll
      for (int j = 0; j < 4; ++j)
        acc[i][j] = __builtin_amdgcn_mfma_f32_16x16x32_f16(af[i], bf[j], acc[i][j], 0, 0, 0);
    __syncthreads();
  }
#pragma unroll
  for (int j = 0; j < 4; ++j) {
    int n = bn * 128 + wn + j * 16 + row;
    float bv = bias[n];
#pragma unroll
    for (int i = 0; i < 4; ++i) {
      int mbase = bm * 128 + wm + i * 16 + (lane >> 4) * 4;
#pragma unroll
      for (int r = 0; r < 4; ++r) {
        float v = acc[i][j][r] + bv;
        v = fmaxf(v, 0.f);
        Eout[(size_t)(mbase + r) * 1024 + n] = (f16)v;
      }
    }
  }
}

// ---------------------------------------------------------------------------
// Out = Hseq @ W_out + b_out, scatter rows m=t*128+b -> out[b][t][:] fp32
// ---------------------------------------------------------------------------
__global__ __launch_bounds__(256) void out_gemm(const f16* __restrict__ Hs,
                                                const f16* __restrict__ WT,
                                                const float* __restrict__ bias,
                                                float* __restrict__ Out) {
  __shared__ f16 As[128][40];
  __shared__ f16 Bs[128][40];
  const int bm = blockIdx.x, bn = blockIdx.y;
  const int tid = threadIdx.x, lane = tid & 63, wave = tid >> 6;
  const int wm = (wave >> 1) * 64, wn = (wave & 1) * 64;
  const int row = lane & 15, q8 = (lane >> 4) * 8;
  f32x4 acc[4][4] = {};
  for (int k0 = 0; k0 < UNITS; k0 += 32) {
    for (int i = tid; i < 512; i += 256) {
      int r = i >> 2, cc = (i & 3) * 8;
      *(f16x8*)&As[r][cc] = *(const f16x8*)(Hs + (size_t)(bm * 128 + r) * 1024 + k0 + cc);
    }
    for (int i = tid; i < 512; i += 256) {
      int r = i >> 2, cc = (i & 3) * 8;
      *(f16x8*)&Bs[r][cc] = *(const f16x8*)(WT + (size_t)(bn * 128 + r) * 1024 + k0 + cc);
    }
    __syncthreads();
    f16x8 af[4], bf[4];
#pragma unroll
    for (int i = 0; i < 4; ++i) af[i] = *(const f16x8*)&As[wm + i * 16 + row][q8];
#pragma unroll
    for (int j = 0; j < 4; ++j) bf[j] = *(const f16x8*)&Bs[wn + j * 16 + row][q8];
#pragma unroll
    for (int i = 0; i < 4; ++i)
#pragma unroll
      for (int j = 0; j < 4; ++j)
        acc[i][j] = __builtin_amdgcn_mfma_f32_16x16x32_f16(af[i], bf[j], acc[i][j], 0, 0, 0);
    __syncthreads();
  }
#pragma unroll
  for (int j = 0; j < 4; ++j) {
    int n = bn * 128 + wn + j * 16 + row;
    float bv = bias[n];
#pragma unroll
    for (int i = 0; i < 4; ++i) {
      int mbase = bm * 128 + wm + i * 16 + (lane >> 4) * 4;
#pragma unroll
      for (int r = 0; r < 4; ++r) {
        int m = mbase + r;
        int b = m & 127, t = m >> 7;
        Out[((size_t)b * TSTEPS + t) * 1024 + n] = acc[i][j][r] + bv;
      }
    }
  }
}

// ---------------------------------------------------------------------------
// Persistent cooperative recurrent kernel.
// 256 WGs x 512 threads (8 waves). WG w owns units u0=4w..4w+3 (16 z-columns:
// col j in [0,16): gate g=j>>2, unit u0+(j&3)). W_k^T/W_r^T slices live in LDS
// pre-swizzled into MFMA B-fragment order ([mat][kiter][lane][8] f16 = 64 KB,
// lane-contiguous 16B reads: conflict-free). Per step: z = e_t@Wk + h@Wr + b_r
// via 16x16x32 f16 MFMA (wave w handles rows 16w..16w+15; A-fragments read
// straight from global/L2, 64B-per-row coalesced). Gates mixed via __shfl
// (cols j, j+4, j+8, j+12 sit 4 lanes apart in C-layout). c stays in VGPRs
// (duplicated across the 4 gate lane-groups). h_new written f16 to ping-pong
// buffer + Hseq.
//
// Grid barrier: hand-rolled (cg::grid_sync measured ~100us/step -> 99% of
// kernel time). Monotonic-count barrier: 8 cacheline-padded agent-scope
// counters (arrival spread by blockIdx&7, 32 RMWs/line), every WG's thread 0
// polls the 8-counter sum until >= (t+1)*NWG, s_sleep(2) backoff. No reset,
// no sense reversal -> no reset race. __threadfence() before arrival
// (release: writeback h to LLC) and after exit (acquire: invalidate stale L1/
// L2 h lines) replicate the ordering ockl's grid sync provided.
// ---------------------------------------------------------------------------
__global__ void __launch_bounds__(512, 1)
recur(const f16* __restrict__ E, const f16* __restrict__ WkT,
      const f16* __restrict__ WrT, const float* __restrict__ b_r,
      const float* __restrict__ c0, f16* h_buf, f16* __restrict__ Hseq,
      unsigned* bar) {
  __shared__ f16 Ws[2][32][64][8]; // exactly 64 KB
  const int tid = threadIdx.x, lane = tid & 63, wave = tid >> 6;
  const int u0 = blockIdx.x * 4;

  // Pre-swizzle weight slices into fragment order.
  const f16* WT[2] = {WkT, WrT};
  for (int i = tid; i < 2 * 32 * 64; i += 512) {
    int mat = i >> 11, kk = (i >> 6) & 31, l = i & 63;
    int j = l & 15;
    int col = (j >> 2) * 1024 + u0 + (j & 3);
    int krow = kk * 32 + (l >> 4) * 8;
    *(f16x8*)&Ws[mat][kk][l][0] = *(const f16x8*)(WT[mat] + (size_t)col * 1024 + krow);
  }

  const int j = lane & 15;
  const float bias = b_r[(j >> 2) * 1024 + u0 + (j & 3)];
  const int qrow = (lane >> 4) * 4; // C-layout row base within 16x16 tile
  const int u = lane & 3;
  const int srcbase = lane & 48;
  const int arow = wave * 16 + (lane & 15); // A-operand row (batch index)
  const int koff = (lane >> 4) * 8;

  float c[4];
#pragma unroll
  for (int r = 0; r < 4; ++r)
    c[r] = c0[(size_t)(wave * 16 + qrow + r) * 1024 + u0 + u];

  __syncthreads();

  for (int t = 0; t < TSTEPS; ++t) {
    const f16* hc = h_buf + (size_t)(t & 1) * (BATCH * UNITS);
    f16* hn = h_buf + (size_t)((t + 1) & 1) * (BATCH * UNITS);
    const f16* ea = E + (size_t)t * (BATCH * UNITS) + (size_t)arow * 1024 + koff;
    const f16* ha = hc + (size_t)arow * 1024 + koff;

    f32x4 acc = {0.f, 0.f, 0.f, 0.f};
#pragma unroll 8
    for (int kk = 0; kk < 32; ++kk) {
      f16x8 ae = *(const f16x8*)(ea + kk * 32);
      f16x8 ah = *(const f16x8*)(ha + kk * 32);
      f16x8 bk = *(const f16x8*)&Ws[0][kk][lane][0];
      f16x8 br = *(const f16x8*)&Ws[1][kk][lane][0];
      acc = __builtin_amdgcn_mfma_f32_16x16x32_f16(ae, bk, acc, 0, 0, 0);
      acc = __builtin_amdgcn_mfma_f32_16x16x32_f16(ah, br, acc, 0, 0, 0);
    }

    float hv[4];
#pragma unroll
    for (int r = 0; r < 4; ++r) {
      float z = acc[r] + bias;
      float zi = __shfl(z, srcbase + u);
      float zf = __shfl(z, srcbase + 4 + u);
      float zg = __shfl(z, srcbase + 8 + u);
      float zo = __shfl(z, srcbase + 12 + u);
      float ig = sigm(zi), fg = sigm(zf), gg = tanh_f(zg), og = sigm(zo);
      float cn = fg * c[r] + ig * gg;
      c[r] = cn;
      hv[r] = og * tanh_f(cn);
    }
    if ((lane & 12) == 0) { // one lane-group per (row, unit)
#pragma unroll
      for (int r = 0; r < 4; ++r) {
        int m = wave * 16 + qrow + r;
        f16 hf = (f16)hv[r];
        hn[(size_t)m * 1024 + u0 + u] = hf;
        Hseq[((size_t)t * BATCH + m) * 1024 + u0 + u] = hf;
      }
    }

    // ---- fast grid barrier ----
    __threadfence();   // release: h_new drained to device coherence point
    __syncthreads();   // all waves of this WG fenced before arrival
    if (tid == 0) {
      __hip_atomic_fetch_add(bar + ((blockIdx.x & 7) << 6), 1u,
                             __ATOMIC_RELAXED, __HIP_MEMORY_SCOPE_AGENT);
      const unsigned tgt = (unsigned)(t + 1) * NWG;
      for (;;) {
        unsigned s = 0;
#pragma unroll
        for (int i = 0; i < 8; ++i)
          s += __hip_atomic_load(bar + (i << 6), __ATOMIC_RELAXED,
                                 __HIP_MEMORY_SCOPE_AGENT);
        if (s >= tgt) break;
        __builtin_amdgcn_s_sleep(2);
      }
    }
    __syncthreads();
    __threadfence();   // acquire: invalidate stale cached h lines
  }
}

// ---------------------------------------------------------------------------
extern "C" void kernel_launch(void* const* d_in, const int* in_sizes, int n_in,
                              void* d_out, int out_size, void* d_ws, size_t ws_size,
                              hipStream_t stream) {
  const float* h0 = (const float*)d_in[0];
  const float* c0 = (const float*)d_in[1];
  const float* X = (const float*)d_in[2];
  const float* W_emb = (const float*)d_in[3];
  const float* b_emb = (const float*)d_in[4];
  const float* W_k = (const float*)d_in[5];
  const float* W_r = (const float*)d_in[6];
  const float* b_r = (const float*)d_in[7];
  const float* W_out = (const float*)d_in[8];
  const float* b_out = (const float*)d_in[9];
  float* Out = (float*)d_out;

  char* w = (char*)d_ws;
  const size_t OFF_WKT = 0;
  const size_t OFF_WRT = OFF_WKT + (size_t)4096 * 1024 * 2;
  const size_t OFF_WEMBT = OFF_WRT + (size_t)4096 * 1024 * 2;
  const size_t OFF_WOUTT = OFF_WEMBT + (size_t)1024 * 1024 * 2;
  const size_t OFF_E = OFF_WOUTT + (size_t)1024 * 1024 * 2;
  const size_t OFF_H = OFF_E + (size_t)MTOT * 1024 * 2;
  const size_t OFF_HB = OFF_H + (size_t)MTOT * 1024 * 2;
  const size_t OFF_BAR = OFF_HB + (size_t)2 * BATCH * UNITS * 2;
  const size_t NEED = OFF_BAR + 8 * 64 * sizeof(unsigned);
  if (ws_size < NEED) {
    // workspace too small for this plan — fail loudly-but-cleanly
    hipMemsetAsync(d_out, 0, (size_t)out_size * 4, stream);
    return;
  }
  f16* WkT = (f16*)(w + OFF_WKT);
  f16* WrT = (f16*)(w + OFF_WRT);
  f16* WembT = (f16*)(w + OFF_WEMBT);
  f16* WoutT = (f16*)(w + OFF_WOUTT);
  f16* E = (f16*)(w + OFF_E);
  f16* Hs = (f16*)(w + OFF_H);
  f16* Hb = (f16*)(w + OFF_HB);
  unsigned* bar = (unsigned*)(w + OFF_BAR);

  hipMemsetAsync(w + OFF_BAR, 0, 8 * 64 * sizeof(unsigned), stream);

  transpose_cvt<<<dim3(128, 32), dim3(32, 8), 0, stream>>>(W_k, WkT, 1024, 4096);
  transpose_cvt<<<dim3(128, 32), dim3(32, 8), 0, stream>>>(W_r, WrT, 1024, 4096);
  transpose_cvt<<<dim3(32, 32), dim3(32, 8), 0, stream>>>(W_emb, WembT, 1024, 1024);
  transpose_cvt<<<dim3(32, 32), dim3(32, 8), 0, stream>>>(W_out, WoutT, 1024, 1024);
  cvt_h0<<<dim3(512), dim3(256), 0, stream>>>(h0, Hb);
  emb_gemm<<<dim3(512, 8), dim3(256), 0, stream>>>(X, WembT, b_emb, E);

  const f16* Ep = E;
  const f16* WkTp = WkT;
  const f16* WrTp = WrT;
  const float* brp = b_r;
  const float* c0p = c0;
  f16* Hbp = Hb;
  f16* Hsp = Hs;
  unsigned* barp = bar;
  void* args[] = {&Ep, &WkTp, &WrTp, &brp, &c0p, &Hbp, &Hsp, &barp};
  hipLaunchCooperativeKernel(reinterpret_cast<void*>(recur), dim3(256), dim3(512),
                             args, 0, stream);

  out_gemm<<<dim3(512, 8), dim3(256), 0, stream>>>(Hs, WoutT, b_out, Out);
}

// Round 2
// 14007.904 us; speedup vs baseline: 3.9533x; 3.9266x over previous
//
#include <hip/hip_runtime.h>

typedef _Float16 f16;
typedef _Float16 f16x8 __attribute__((ext_vector_type(8)));
typedef float f32x4 __attribute__((ext_vector_type(4)));

// Problem constants (fixed by reference): B=128, T=512, UNITS=OUT=1024
#define BATCH 128
#define TSTEPS 512
#define UNITS 1024
#define MTOT (BATCH * TSTEPS) // 65536
#define NWG 256               // recur grid size (1 WG / CU, cooperative)

__device__ __forceinline__ float sigm(float x) { return 1.f / (1.f + __expf(-x)); }
__device__ __forceinline__ float tanh_f(float x) { return 2.f / (1.f + __expf(-2.f * x)) - 1.f; }

// ---------------------------------------------------------------------------
// Transpose + fp32->fp16 convert: in[K][N] -> out[N][K]
// ---------------------------------------------------------------------------
__global__ void transpose_cvt(const float* __restrict__ in, f16* __restrict__ out,
                              int K, int N) {
  __shared__ float tile[32][33];
  int bx = blockIdx.x * 32, by = blockIdx.y * 32;
  int x = threadIdx.x, y = threadIdx.y;
#pragma unroll
  for (int i = 0; i < 32; i += 8)
    tile[y + i][x] = in[(size_t)(by + y + i) * N + bx + x];
  __syncthreads();
#pragma unroll
  for (int i = 0; i < 32; i += 8)
    out[(size_t)(bx + y + i) * K + by + x] = (f16)tile[x][y + i];
}

// ---------------------------------------------------------------------------
// h0 fp32 -> f16 into h ping-pong buffer slot 0
// ---------------------------------------------------------------------------
__global__ void cvt_h0(const float* __restrict__ h0, f16* __restrict__ hb) {
  int i = blockIdx.x * blockDim.x + threadIdx.x;
  if (i < BATCH * UNITS) hb[i] = (f16)h0[i];
}

// ---------------------------------------------------------------------------
// E = relu(X @ W_emb + b_emb), stored f16, rows ordered m = t*128 + b
// X is target_inputs [128][513][1024] fp32; WT is W_emb^T f16 [1024][1024]
// ---------------------------------------------------------------------------
__global__ __launch_bounds__(256) void emb_gemm(const float* __restrict__ X,
                                                const f16* __restrict__ WT,
                                                const float* __restrict__ bias,
                                                f16* __restrict__ Eout) {
  __shared__ f16 As[128][40]; // +8 pad: 2-way LDS aliasing only (free)
  __shared__ f16 Bs[128][40];
  const int bm = blockIdx.x, bn = blockIdx.y;
  const int tid = threadIdx.x, lane = tid & 63, wave = tid >> 6;
  const int wm = (wave >> 1) * 64, wn = (wave & 1) * 64;
  const int row = lane & 15, q8 = (lane >> 4) * 8;
  f32x4 acc[4][4] = {};
  for (int k0 = 0; k0 < UNITS; k0 += 32) {
    for (int i = tid; i < 512; i += 256) {
      int r = i >> 2, cc = (i & 3) * 8;
      int m = bm * 128 + r;
      int b = m & 127, t = m >> 7;
      const float* src = X + (size_t)(b * 513 + t) * 1024 + k0 + cc;
      float4 v0 = *(const float4*)src;
      float4 v1 = *(const float4*)(src + 4);
      f16x8 v = {(f16)v0.x, (f16)v0.y, (f16)v0.z, (f16)v0.w,
                 (f16)v1.x, (f16)v1.y, (f16)v1.z, (f16)v1.w};
      *(f16x8*)&As[r][cc] = v;
    }
    for (int i = tid; i < 512; i += 256) {
      int r = i >> 2, cc = (i & 3) * 8;
      *(f16x8*)&Bs[r][cc] = *(const f16x8*)(WT + (size_t)(bn * 128 + r) * 1024 + k0 + cc);
    }
    __syncthreads();
    f16x8 af[4], bf[4];
#pragma unroll
    for (int i = 0; i < 4; ++i) af[i] = *(const f16x8*)&As[wm + i * 16 + row][q8];
#pragma unroll
    for (int j = 0; j < 4; ++j) bf[j] = *(const f16x8*)&Bs[wn + j * 16 + row][q8];
#pragma unroll
    for (int i = 0; i < 4; ++i)
#pragma unroll
      for (int j = 0; j < 4; ++j)
        acc[i][j] = __builtin_amdgcn_mfma_f32_16x16x32_f16(af[i], bf[j], acc[i][j], 0, 0, 0);
    __syncthreads();
  }
#pragma unroll
  for (int j = 0; j < 4; ++j) {
    int n = bn * 128 + wn + j * 16 + row;
    float bv = bias[n];
#pragma unroll
    for (int i = 0; i < 4; ++i) {
      int mbase = bm * 128 + wm + i * 16 + (lane >> 4) * 4;
#pragma unroll
      for (int r = 0; r < 4; ++r) {
        float v = acc[i][j][r] + bv;
        v = fmaxf(v, 0.f);
        Eout[(size_t)(mbase + r) * 1024 + n] = (f16)v;
      }
    }
  }
}

// ---------------------------------------------------------------------------
// Out = Hseq @ W_out + b_out, scatter rows m=t*128+b -> out[b][t][:] fp32
// ---------------------------------------------------------------------------
__global__ __launch_bounds__(256) void out_gemm(const f16* __restrict__ Hs,
                                                const f16* __restrict__ WT,
                                                const float* __restrict__ bias,
                                                float* __restrict__ Out) {
  __shared__ f16 As[128][40];
  __shared__ f16 Bs[128][40];
  const int bm = blockIdx.x, bn = blockIdx.y;
  const int tid = threadIdx.x, lane = tid & 63, wave = tid >> 6;
  const int wm = (wave >> 1) * 64, wn = (wave & 1) * 64;
  const int row = lane & 15, q8 = (lane >> 4) * 8;
  f32x4 acc[4][4] = {};
  for (int k0 = 0; k0 < UNITS; k0 += 32) {
    for (int i = tid; i < 512; i += 256) {
      int r = i >> 2, cc = (i & 3) * 8;
      *(f16x8*)&As[r][cc] = *(const f16x8*)(Hs + (size_t)(bm * 128 + r) * 1024 + k0 + cc);
    }
    for (int i = tid; i < 512; i += 256) {
      int r = i >> 2, cc = (i & 3) * 8;
      *(f16x8*)&Bs[r][cc] = *(const f16x8*)(WT + (size_t)(bn * 128 + r) * 1024 + k0 + cc);
    }
    __syncthreads();
    f16x8 af[4], bf[4];
#pragma unroll
    for (int i = 0; i < 4; ++i) af[i] = *(const f16x8*)&As[wm + i * 16 + row][q8];
#pragma unroll
    for (int j = 0; j < 4; ++j) bf[j] = *(const f16x8*)&Bs[wn + j * 16 + row][q8];
#pragma unroll
    for (int i = 0; i < 4; ++i)
#pragma unroll
      for (int j = 0; j < 4; ++j)
        acc[i][j] = __builtin_amdgcn_mfma_f32_16x16x32_f16(af[i], bf[j], acc[i][j], 0, 0, 0);
    __syncthreads();
  }
#pragma unroll
  for (int j = 0; j < 4; ++j) {
    int n = bn * 128 + wn + j * 16 + row;
    float bv = bias[n];
#pragma unroll
    for (int i = 0; i < 4; ++i) {
      int mbase = bm * 128 + wm + i * 16 + (lane >> 4) * 4;
#pragma unroll
      for (int r = 0; r < 4; ++r) {
        int m = mbase + r;
        int b = m & 127, t = m >> 7;
        Out[((size_t)b * TSTEPS + t) * 1024 + n] = acc[i][j][r] + bv;
      }
    }
  }
}

// ---------------------------------------------------------------------------
// Persistent cooperative recurrent kernel.
// 256 WGs x 512 threads (8 waves). WG w owns units u0=4w..4w+3 (16 z-columns:
// col j in [0,16): gate g=j>>2, unit u0+(j&3)). W_k^T/W_r^T slices live in LDS
// pre-swizzled into MFMA B-fragment order ([mat][kiter][lane][8] f16 = 64 KB,
// lane-contiguous 16B reads: conflict-free). Per step: z = e_t@Wk + h@Wr + b_r
// via 16x16x32 f16 MFMA (wave w handles rows 16w..16w+15; A-fragments read
// straight from global/L2, 64B-per-row coalesced). Gates mixed via __shfl
// (cols j, j+4, j+8, j+12 sit 4 lanes apart in C-layout). c stays in VGPRs
// (duplicated across the 4 gate lane-groups). h_new written f16 to ping-pong
// buffer + Hseq.
//
// ZERO-FENCE h exchange (R2): R1 showed the barrier mechanism was not the
// cost (hand-rolled == ockl, both ~106us/step). Shared suspect: per-wave
// __threadfence() = agent-scope release/acquire = L2 writeback + invalidate
// walks on every wave, every step (4096 cache-maintenance ops/step). This
// version has NO fences at all: the h ping-pong goes through agent-scope
// RELAXED atomics, which lower to cache-BYPASSING (sc0 sc1) accesses visible
// at the LLC directly:
//   - h stores: 2B __hip_atomic_store (write-through to LLC)
//   - h loads:  2x8B __hip_atomic_load (bypass stale L1/L2, read LLC)
//   - ordering: pre-arrival __syncthreads drains vmcnt(0) for all waves, so
//     write-through stores are at the LLC before thread0's arrival add; any
//     poller observing the count observes the data. Hseq stays normal cached
//     (read only by out_gemm after kernel end; inter-kernel release covers it).
// Barrier: monotonic 8-cacheline-spread counters, relaxed atomics, s_sleep
// backoff (unchanged from R1).
// ---------------------------------------------------------------------------
__global__ void __launch_bounds__(512, 1)
recur(const f16* __restrict__ E, const f16* __restrict__ WkT,
      const f16* __restrict__ WrT, const float* __restrict__ b_r,
      const float* __restrict__ c0, f16* h_buf, f16* __restrict__ Hseq,
      unsigned* bar) {
  __shared__ f16 Ws[2][32][64][8]; // exactly 64 KB
  const int tid = threadIdx.x, lane = tid & 63, wave = tid >> 6;
  const int u0 = blockIdx.x * 4;

  // Pre-swizzle weight slices into fragment order.
  const f16* WT[2] = {WkT, WrT};
  for (int i = tid; i < 2 * 32 * 64; i += 512) {
    int mat = i >> 11, kk = (i >> 6) & 31, l = i & 63;
    int j = l & 15;
    int col = (j >> 2) * 1024 + u0 + (j & 3);
    int krow = kk * 32 + (l >> 4) * 8;
    *(f16x8*)&Ws[mat][kk][l][0] = *(const f16x8*)(WT[mat] + (size_t)col * 1024 + krow);
  }

  const int j = lane & 15;
  const float bias = b_r[(j >> 2) * 1024 + u0 + (j & 3)];
  const int qrow = (lane >> 4) * 4; // C-layout row base within 16x16 tile
  const int u = lane & 3;
  const int srcbase = lane & 48;
  const int arow = wave * 16 + (lane & 15); // A-operand row (batch index)
  const int koff = (lane >> 4) * 8;

  float c[4];
#pragma unroll
  for (int r = 0; r < 4; ++r)
    c[r] = c0[(size_t)(wave * 16 + qrow + r) * 1024 + u0 + u];

  __syncthreads();

  union U16x8 {
    unsigned long long q[2];
    f16x8 v;
  };

  for (int t = 0; t < TSTEPS; ++t) {
    const f16* hc = h_buf + (size_t)(t & 1) * (BATCH * UNITS);
    f16* hn = h_buf + (size_t)((t + 1) & 1) * (BATCH * UNITS);
    const f16* ea = E + (size_t)t * (BATCH * UNITS) + (size_t)arow * 1024 + koff;
    const unsigned long long* ha64 =
        (const unsigned long long*)(hc + (size_t)arow * 1024 + koff);

    f32x4 acc = {0.f, 0.f, 0.f, 0.f};
#pragma unroll 8
    for (int kk = 0; kk < 32; ++kk) {
      f16x8 ae = *(const f16x8*)(ea + kk * 32);
      U16x8 hu;
      hu.q[0] = __hip_atomic_load(ha64 + kk * 8, __ATOMIC_RELAXED,
                                  __HIP_MEMORY_SCOPE_AGENT);
      hu.q[1] = __hip_atomic_load(ha64 + kk * 8 + 1, __ATOMIC_RELAXED,
                                  __HIP_MEMORY_SCOPE_AGENT);
      f16x8 bk = *(const f16x8*)&Ws[0][kk][lane][0];
      f16x8 br = *(const f16x8*)&Ws[1][kk][lane][0];
      acc = __builtin_amdgcn_mfma_f32_16x16x32_f16(ae, bk, acc, 0, 0, 0);
      acc = __builtin_amdgcn_mfma_f32_16x16x32_f16(hu.v, br, acc, 0, 0, 0);
    }

    float hv[4];
#pragma unroll
    for (int r = 0; r < 4; ++r) {
      float z = acc[r] + bias;
      float zi = __shfl(z, srcbase + u);
      float zf = __shfl(z, srcbase + 4 + u);
      float zg = __shfl(z, srcbase + 8 + u);
      float zo = __shfl(z, srcbase + 12 + u);
      float ig = sigm(zi), fg = sigm(zf), gg = tanh_f(zg), og = sigm(zo);
      float cn = fg * c[r] + ig * gg;
      c[r] = cn;
      hv[r] = og * tanh_f(cn);
    }
    if ((lane & 12) == 0) { // one lane-group per (row, unit)
#pragma unroll
      for (int r = 0; r < 4; ++r) {
        int m = wave * 16 + qrow + r;
        f16 hf = (f16)hv[r];
        __hip_atomic_store((unsigned short*)(hn + (size_t)m * 1024 + u0 + u),
                           __builtin_bit_cast(unsigned short, hf),
                           __ATOMIC_RELAXED, __HIP_MEMORY_SCOPE_AGENT);
        Hseq[((size_t)t * BATCH + m) * 1024 + u0 + u] = hf;
      }
    }

    // ---- fast grid barrier (no fences: h exchange is via LLC atomics) ----
    __syncthreads(); // drains vmcnt(0) in every wave -> h stores at LLC
    if (tid == 0) {
      __hip_atomic_fetch_add(bar + ((blockIdx.x & 7) << 6), 1u,
                             __ATOMIC_RELAXED, __HIP_MEMORY_SCOPE_AGENT);
      const unsigned tgt = (unsigned)(t + 1) * NWG;
      for (;;) {
        unsigned s = 0;
#pragma unroll
        for (int i = 0; i < 8; ++i)
          s += __hip_atomic_load(bar + (i << 6), __ATOMIC_RELAXED,
                                 __HIP_MEMORY_SCOPE_AGENT);
        if (s >= tgt) break;
        __builtin_amdgcn_s_sleep(2);
      }
    }
    __syncthreads();
  }
}

// ---------------------------------------------------------------------------
extern "C" void kernel_launch(void* const* d_in, const int* in_sizes, int n_in,
                              void* d_out, int out_size, void* d_ws, size_t ws_size,
                              hipStream_t stream) {
  const float* h0 = (const float*)d_in[0];
  const float* c0 = (const float*)d_in[1];
  const float* X = (const float*)d_in[2];
  const float* W_emb = (const float*)d_in[3];
  const float* b_emb = (const float*)d_in[4];
  const float* W_k = (const float*)d_in[5];
  const float* W_r = (const float*)d_in[6];
  const float* b_r = (const float*)d_in[7];
  const float* W_out = (const float*)d_in[8];
  const float* b_out = (const float*)d_in[9];
  float* Out = (float*)d_out;

  char* w = (char*)d_ws;
  const size_t OFF_WKT = 0;
  const size_t OFF_WRT = OFF_WKT + (size_t)4096 * 1024 * 2;
  const size_t OFF_WEMBT = OFF_WRT + (size_t)4096 * 1024 * 2;
  const size_t OFF_WOUTT = OFF_WEMBT + (size_t)1024 * 1024 * 2;
  const size_t OFF_E = OFF_WOUTT + (size_t)1024 * 1024 * 2;
  const size_t OFF_H = OFF_E + (size_t)MTOT * 1024 * 2;
  const size_t OFF_HB = OFF_H + (size_t)MTOT * 1024 * 2;
  const size_t OFF_BAR = OFF_HB + (size_t)2 * BATCH * UNITS * 2;
  const size_t NEED = OFF_BAR + 8 * 64 * sizeof(unsigned);
  if (ws_size < NEED) {
    // workspace too small for this plan — fail loudly-but-cleanly
    hipMemsetAsync(d_out, 0, (size_t)out_size * 4, stream);
    return;
  }
  f16* WkT = (f16*)(w + OFF_WKT);
  f16* WrT = (f16*)(w + OFF_WRT);
  f16* WembT = (f16*)(w + OFF_WEMBT);
  f16* WoutT = (f16*)(w + OFF_WOUTT);
  f16* E = (f16*)(w + OFF_E);
  f16* Hs = (f16*)(w + OFF_H);
  f16* Hb = (f16*)(w + OFF_HB);
  unsigned* bar = (unsigned*)(w + OFF_BAR);

  hipMemsetAsync(w + OFF_BAR, 0, 8 * 64 * sizeof(unsigned), stream);

  transpose_cvt<<<dim3(128, 32), dim3(32, 8), 0, stream>>>(W_k, WkT, 1024, 4096);
  transpose_cvt<<<dim3(128, 32), dim3(32, 8), 0, stream>>>(W_r, WrT, 1024, 4096);
  transpose_cvt<<<dim3(32, 32), dim3(32, 8), 0, stream>>>(W_emb, WembT, 1024, 1024);
  transpose_cvt<<<dim3(32, 32), dim3(32, 8), 0, stream>>>(W_out, WoutT, 1024, 1024);
  cvt_h0<<<dim3(512), dim3(256), 0, stream>>>(h0, Hb);
  emb_gemm<<<dim3(512, 8), dim3(256), 0, stream>>>(X, WembT, b_emb, E);

  const f16* Ep = E;
  const f16* WkTp = WkT;
  const f16* WrTp = WrT;
  const float* brp = b_r;
  const float* c0p = c0;
  f16* Hbp = Hb;
  f16* Hsp = Hs;
  unsigned* barp = bar;
  void* args[] = {&Ep, &WkTp, &WrTp, &brp, &c0p, &Hbp, &Hsp, &barp};
  hipLaunchCooperativeKernel(reinterpret_cast<void*>(recur), dim3(256), dim3(512),
                             args, 0, stream);

  out_gemm<<<dim3(512, 8), dim3(256), 0, stream>>>(Hs, WoutT, b_out, Out);
}